// Round 1
// baseline (378.057 us; speedup 1.0000x reference)
//
#include <hip/hip_runtime.h>

#define NGRID 512
#define NV (NGRID * NGRID)          // 262144 = 2^18
#define NB 4                        // batch
#define NVIEWS 4
#define FEPS 1e-6f

static constexpr size_t NVF3 = (size_t)NV * 3;                 // floats per (batch,view) block
static constexpr size_t VERTS_FLOATS = (size_t)NVIEWS * NB * NVF3;  // 12,582,912
static constexpr size_t LAP_OFF = 2 * VERTS_FLOATS;            // 25,165,824
static constexpr size_t FLAT_OFF = LAP_OFF + 1;

// ---------------------------------------------------------------------------
__global__ void init_losses(float* __restrict__ out) {
    if (threadIdx.x == 0) {
        out[LAP_OFF] = 0.0f;
        out[FLAT_OFF] = 0.0f;
    }
}

// ---------------------------------------------------------------------------
// Fused: compute deformed vertices v and write 4 tiled copies; tile texture x4.
// Grid: (nv*3/4/256, B) blocks of 256. Each thread handles one float4 of the
// flat (nv*3) array for one batch.
__global__ __launch_bounds__(256) void v_tex_kernel(
    const float* __restrict__ disp, const float* __restrict__ center,
    const float* __restrict__ tex, const float* __restrict__ tv,
    float* __restrict__ out)
{
    const int j = blockIdx.x * 256 + threadIdx.x;   // float4 index in [0, NV*3/4)
    const int b = blockIdx.y;

    // centroid = tanh(center[b])
    const float c0 = tanhf(center[b * 3 + 0]);
    const float c1 = tanhf(center[b * 3 + 1]);
    const float c2 = tanhf(center[b * 3 + 2]);
    const float carr[3] = {c0, c1, c2};

    const float4* __restrict__ tv4 = (const float4*)tv;
    const float4* __restrict__ d4p = (const float4*)(disp + (size_t)b * NVF3);
    const float4* __restrict__ t4p = (const float4*)(tex + (size_t)b * NVF3);

    const float4 t = tv4[j];
    const float4 d = d4p[j];
    const float4 x = t4p[j];

    const float tvv[4] = {t.x, t.y, t.z, t.w};
    const float dvv[4] = {d.x, d.y, d.z, d.w};
    float vr[4];

    int comp = j % 3;  // (4*j) % 3 == j % 3
#pragma unroll
    for (int l = 0; l < 4; ++l) {
        const float tvl = tvv[l];
        const float s = fabsf(tvl);
        const float sgn = (tvl > 0.0f) ? 1.0f : -1.0f;
        // sigmoid(log(s/(1-s)) + d) = s / (s + (1-s)*exp(-d))
        const float v0 = sgn * (s / (s + (1.0f - s) * expf(-dvv[l])));
        const float c = carr[comp];
        const float pos = fmaxf(v0, 0.0f);
        const float neg = fmaxf(-v0, 0.0f);
        vr[l] = pos * (1.0f - c) - neg * (c + 1.0f) + c;
        comp = (comp == 2) ? 0 : comp + 1;
    }

    const float4 vo = make_float4(vr[0], vr[1], vr[2], vr[3]);
    float4* __restrict__ out4 = (float4*)out;
    const size_t blk4 = NVF3 / 4;  // float4s per (batch,view) block
#pragma unroll
    for (int view = 0; view < NVIEWS; ++view) {
        const size_t base = (size_t)(b * NVIEWS + view) * blk4;
        out4[base + j] = vo;                               // verts_out
        out4[(VERTS_FLOATS / 4) + base + j] = x;           // tex_out
    }
}

// ---------------------------------------------------------------------------
__device__ __forceinline__ float block_reduce_256(float v) {
#pragma unroll
    for (int off = 32; off > 0; off >>= 1) v += __shfl_down(v, off, 64);
    __shared__ float s[4];
    const int lane = threadIdx.x & 63;
    const int wid = threadIdx.x >> 6;
    if (lane == 0) s[wid] = v;
    __syncthreads();
    if (threadIdx.x == 0) v = s[0] + s[1] + s[2] + s[3];
    return v;
}

// ---------------------------------------------------------------------------
// Laplacian loss via grid structure. Neighbors of (r,c):
// (r-1,c),(r+1,c),(r,c-1),(r,c+1),(r-1,c+1),(r+1,c-1) where valid.
// Grid: (NV/256, B). Reads v from out (view 0 of each batch).
__global__ __launch_bounds__(256) void lap_kernel(
    const float* __restrict__ out, float* __restrict__ loss)
{
    const int i = blockIdx.x * 256 + threadIdx.x;   // vertex index
    const int b = blockIdx.y;
    const float* __restrict__ vb = out + (size_t)(b * NVIEWS) * NVF3;

    const int r = i >> 9;
    const int c = i & (NGRID - 1);

    float sx = 0.f, sy = 0.f, sz = 0.f;
    int deg = 0;
#define ADDN(rr, cc)                              \
    {                                             \
        const int jj = ((rr) << 9) | (cc);        \
        sx += vb[jj * 3 + 0];                     \
        sy += vb[jj * 3 + 1];                     \
        sz += vb[jj * 3 + 2];                     \
        deg++;                                    \
    }
    if (r > 0) ADDN(r - 1, c);
    if (r < NGRID - 1) ADDN(r + 1, c);
    if (c > 0) ADDN(r, c - 1);
    if (c < NGRID - 1) ADDN(r, c + 1);
    if (r > 0 && c < NGRID - 1) ADDN(r - 1, c + 1);
    if (r < NGRID - 1 && c > 0) ADDN(r + 1, c - 1);
#undef ADDN

    const float id = 1.0f / (float)deg;
    const float lx = vb[i * 3 + 0] - sx * id;
    const float ly = vb[i * 3 + 1] - sy * id;
    const float lz = vb[i * 3 + 2] - sz * id;
    float val = lx * lx + ly * ly + lz * lz;

    val = block_reduce_256(val);
    if (threadIdx.x == 0) atomicAdd(loss, val * (1.0f / NB));
}

// ---------------------------------------------------------------------------
// Flatness loss. Grid: (ceil(ne/256), B). Gathers 4 vertices per edge from v.
__global__ __launch_bounds__(256) void flat_kernel(
    const float* __restrict__ out,
    const int* __restrict__ v0s, const int* __restrict__ v1s,
    const int* __restrict__ v2s, const int* __restrict__ v3s,
    int ne, float* __restrict__ loss)
{
    const int e = blockIdx.x * 256 + threadIdx.x;
    const int b = blockIdx.y;
    float val = 0.0f;
    if (e < ne) {
        const float* __restrict__ vb = out + (size_t)(b * NVIEWS) * NVF3;
        const int i0 = v0s[e], i1 = v1s[e], i2 = v2s[e], i3 = v3s[e];
        const float p0x = vb[i0 * 3 + 0], p0y = vb[i0 * 3 + 1], p0z = vb[i0 * 3 + 2];
        const float p1x = vb[i1 * 3 + 0], p1y = vb[i1 * 3 + 1], p1z = vb[i1 * 3 + 2];
        const float p2x = vb[i2 * 3 + 0], p2y = vb[i2 * 3 + 1], p2z = vb[i2 * 3 + 2];
        const float p3x = vb[i3 * 3 + 0], p3y = vb[i3 * 3 + 1], p3z = vb[i3 * 3 + 2];

        const float a1x = p1x - p0x, a1y = p1y - p0y, a1z = p1z - p0z;
        const float a1l2 = a1x * a1x + a1y * a1y + a1z * a1z;
        const float a1l1 = sqrtf(a1l2 + FEPS);
        const float inv_a1l2 = 1.0f / (a1l2 + FEPS);

        // component for b1 = p2 - p0
        const float b1x = p2x - p0x, b1y = p2y - p0y, b1z = p2z - p0z;
        const float b1l2 = b1x * b1x + b1y * b1y + b1z * b1z;
        const float b1l1 = sqrtf(b1l2 + FEPS);
        const float ab1 = a1x * b1x + a1y * b1y + a1z * b1z;
        const float cos1 = ab1 / (a1l1 * b1l1 + FEPS);
        const float sin1 = sqrtf(1.0f - cos1 * cos1 + FEPS);
        const float f1 = ab1 * inv_a1l2;
        const float cb1x = b1x - a1x * f1, cb1y = b1y - a1y * f1, cb1z = b1z - a1z * f1;
        const float l1 = b1l1 * sin1;

        // component for b2 = p3 - p0
        const float b2x = p3x - p0x, b2y = p3y - p0y, b2z = p3z - p0z;
        const float b2l2 = b2x * b2x + b2y * b2y + b2z * b2z;
        const float b2l1 = sqrtf(b2l2 + FEPS);
        const float ab2 = a1x * b2x + a1y * b2y + a1z * b2z;
        const float cos2 = ab2 / (a1l1 * b2l1 + FEPS);
        const float sin2 = sqrtf(1.0f - cos2 * cos2 + FEPS);
        const float f2 = ab2 * inv_a1l2;
        const float cb2x = b2x - a1x * f2, cb2y = b2y - a1y * f2, cb2z = b2z - a1z * f2;
        const float l2 = b2l1 * sin2;

        const float cosd = (cb1x * cb2x + cb1y * cb2y + cb1z * cb2z) / (l1 * l2 + FEPS);
        const float t = cosd + 1.0f;
        val = t * t;
    }

    val = block_reduce_256(val);
    if (threadIdx.x == 0) atomicAdd(loss, val * (1.0f / NB));
}

// ---------------------------------------------------------------------------
extern "C" void kernel_launch(void* const* d_in, const int* in_sizes, int n_in,
                              void* d_out, int out_size, void* d_ws, size_t ws_size,
                              hipStream_t stream)
{
    const float* disp   = (const float*)d_in[0];
    const float* center = (const float*)d_in[1];
    const float* tex    = (const float*)d_in[2];
    const float* tv     = (const float*)d_in[3];
    const int*   v0s    = (const int*)d_in[7];
    const int*   v1s    = (const int*)d_in[8];
    const int*   v2s    = (const int*)d_in[9];
    const int*   v3s    = (const int*)d_in[10];
    const int ne = in_sizes[7];

    float* out = (float*)d_out;

    init_losses<<<1, 64, 0, stream>>>(out);

    // NV*3/4 float4s per batch = 196608 -> 768 blocks of 256
    v_tex_kernel<<<dim3(768, NB), 256, 0, stream>>>(disp, center, tex, tv, out);

    lap_kernel<<<dim3(NV / 256, NB), 256, 0, stream>>>(out, out + LAP_OFF);

    flat_kernel<<<dim3((ne + 255) / 256, NB), 256, 0, stream>>>(
        out, v0s, v1s, v2s, v3s, ne, out + FLAT_OFF);
}

// Round 2
// 200.270 us; speedup vs baseline: 1.8877x; 1.8877x over previous
//
#include <hip/hip_runtime.h>

#define NGRID 512
#define NV (NGRID * NGRID)          // 262144
#define NB 4
#define NVIEWS 4
#define FEPS 1e-6f
#define TR 8                        // owned rows per block
#define LDS_ROWS (TR + 2)           // + top/bottom halo
#define ROWF (NGRID * 3)            // 1536 floats per row
#define LDSF (LDS_ROWS * ROWF)      // 15360 floats = 60 KB

static constexpr size_t NVF3 = (size_t)NV * 3;                      // 786432
static constexpr size_t VERTS_FLOATS = (size_t)NVIEWS * NB * NVF3;  // 12,582,912
static constexpr size_t LAP_OFF = 2 * VERTS_FLOATS;
static constexpr size_t FLAT_OFF = LAP_OFF + 1;

// ---------------------------------------------------------------------------
__global__ void init_losses(float* __restrict__ out) {
    if (threadIdx.x == 0) {
        out[LAP_OFF] = 0.0f;
        out[FLAT_OFF] = 0.0f;
    }
}

// ---------------------------------------------------------------------------
__device__ __forceinline__ float3 ldsP(const float* __restrict__ vs, int lr, int c) {
    const int o = lr * ROWF + c * 3;
    return make_float3(vs[o], vs[o + 1], vs[o + 2]);
}

__device__ __forceinline__ float edge_val(float3 p0, float3 p1, float3 p2, float3 p3) {
    const float a1x = p1.x - p0.x, a1y = p1.y - p0.y, a1z = p1.z - p0.z;
    const float a1l2 = a1x * a1x + a1y * a1y + a1z * a1z;
    const float a1l1 = sqrtf(a1l2 + FEPS);
    const float inv_a1l2 = 1.0f / (a1l2 + FEPS);

    const float b1x = p2.x - p0.x, b1y = p2.y - p0.y, b1z = p2.z - p0.z;
    const float b1l2 = b1x * b1x + b1y * b1y + b1z * b1z;
    const float b1l1 = sqrtf(b1l2 + FEPS);
    const float ab1 = a1x * b1x + a1y * b1y + a1z * b1z;
    const float cos1 = ab1 / (a1l1 * b1l1 + FEPS);
    const float sin1 = sqrtf(1.0f - cos1 * cos1 + FEPS);
    const float f1 = ab1 * inv_a1l2;
    const float cb1x = b1x - a1x * f1, cb1y = b1y - a1y * f1, cb1z = b1z - a1z * f1;
    const float l1 = b1l1 * sin1;

    const float b2x = p3.x - p0.x, b2y = p3.y - p0.y, b2z = p3.z - p0.z;
    const float b2l2 = b2x * b2x + b2y * b2y + b2z * b2z;
    const float b2l1 = sqrtf(b2l2 + FEPS);
    const float ab2 = a1x * b2x + a1y * b2y + a1z * b2z;
    const float cos2 = ab2 / (a1l1 * b2l1 + FEPS);
    const float sin2 = sqrtf(1.0f - cos2 * cos2 + FEPS);
    const float f2 = ab2 * inv_a1l2;
    const float cb2x = b2x - a1x * f2, cb2y = b2y - a1y * f2, cb2z = b2z - a1z * f2;
    const float l2 = b2l1 * sin2;

    const float cosd = (cb1x * cb2x + cb1y * cb2y + cb1z * cb2z) / (l1 * l2 + FEPS);
    const float t = cosd + 1.0f;
    return t * t;
}

// ---------------------------------------------------------------------------
// Mega-kernel: one block = (8-row tile, batch). Stages v (with 1-row halo)
// in LDS via recompute, writes verts x4 views + tex x4 views, computes lap
// and flat-loss contributions for the owned rows. Grid: (64, NB) x 256.
__global__ __launch_bounds__(256, 2) void mesh_fused_kernel(
    const float* __restrict__ disp, const float* __restrict__ center,
    const float* __restrict__ tex, const float* __restrict__ tv,
    float* __restrict__ out)
{
    __shared__ float vs[LDSF];
    const int tid = threadIdx.x;
    const int b = blockIdx.y;
    const int R0 = blockIdx.x * TR;

    const float c0 = tanhf(center[b * 3 + 0]);
    const float c1 = tanhf(center[b * 3 + 1]);
    const float c2 = tanhf(center[b * 3 + 2]);
    const float carr[3] = {c0, c1, c2};

    // ---- Stage v for rows [R0-1, R0+TR] into LDS (float4 vectorized) ----
    {
        const float4* __restrict__ tv4 = (const float4*)tv;
        const float4* __restrict__ d4p = (const float4*)(disp + (size_t)b * NVF3);
        float4* __restrict__ vs4 = (float4*)vs;
        const int start4 = (R0 - 1) * (ROWF / 4);          // may be negative (tile 0)
        for (int ff4 = tid; ff4 < LDSF / 4; ff4 += 256) {
            const int g4 = start4 + ff4;
            if (g4 < 0 || g4 >= (int)(NVF3 / 4)) continue;
            const float4 t = tv4[g4];
            const float4 d = d4p[g4];
            const float tvv[4] = {t.x, t.y, t.z, t.w};
            const float dvv[4] = {d.x, d.y, d.z, d.w};
            float vr[4];
            int comp = ff4 % 3;   // (4*g4)%3 == g4%3 == ff4%3 (start4 % 3 == 0)
#pragma unroll
            for (int l = 0; l < 4; ++l) {
                const float tvl = tvv[l];
                const float s = fabsf(tvl);
                const float sgn = (tvl > 0.0f) ? 1.0f : -1.0f;
                const float v0 = sgn * (s / (s + (1.0f - s) * expf(-dvv[l])));
                const float c = carr[comp];
                const float pos = fmaxf(v0, 0.0f);
                const float neg = fmaxf(-v0, 0.0f);
                vr[l] = pos * (1.0f - c) - neg * (c + 1.0f) + c;
                comp = (comp == 2) ? 0 : comp + 1;
            }
            vs4[ff4] = make_float4(vr[0], vr[1], vr[2], vr[3]);
        }
    }
    __syncthreads();

    // ---- Write verts x4 views + tex x4 views for owned rows ----
    {
        const float4* __restrict__ vs4 = (const float4*)vs;
        const float4* __restrict__ t4p = (const float4*)(tex + (size_t)b * NVF3);
        float4* __restrict__ out4 = (float4*)out;
        const size_t blk4 = NVF3 / 4;                       // 196608
        const int tile_base4 = R0 * (ROWF / 4);             // float4 offset of row R0
#pragma unroll 1
        for (int q = tid; q < TR * ROWF / 4; q += 256) {
            const float4 vo = vs4[ROWF / 4 + q];            // skip halo row
            const float4 tx = t4p[tile_base4 + q];
            const size_t pos4 = (size_t)tile_base4 + q;
#pragma unroll
            for (int view = 0; view < NVIEWS; ++view) {
                const size_t base = (size_t)(b * NVIEWS + view) * blk4;
                out4[base + pos4] = vo;
                out4[(VERTS_FLOATS / 4) + base + pos4] = tx;
            }
        }
    }

    // ---- Lap + flat losses for owned rows (reads LDS only) ----
    float lap_sum = 0.0f, flat_sum = 0.0f;
    for (int it = 0; it < TR * NGRID / 256; ++it) {
        const int idx = it * 256 + tid;
        const int r_off = idx >> 9;            // 0..TR-1
        const int c = idx & (NGRID - 1);
        const int gr = R0 + r_off;             // global row
        const int lr = r_off + 1;              // LDS row

        const float3 pc = ldsP(vs, lr, c);

        // Laplacian
        {
            float sx = 0.f, sy = 0.f, sz = 0.f;
            int deg = 0;
            if (gr > 0)               { float3 p = ldsP(vs, lr - 1, c);     sx += p.x; sy += p.y; sz += p.z; deg++; }
            if (gr < NGRID - 1)       { float3 p = ldsP(vs, lr + 1, c);     sx += p.x; sy += p.y; sz += p.z; deg++; }
            if (c > 0)                { float3 p = ldsP(vs, lr, c - 1);     sx += p.x; sy += p.y; sz += p.z; deg++; }
            if (c < NGRID - 1)        { float3 p = ldsP(vs, lr, c + 1);     sx += p.x; sy += p.y; sz += p.z; deg++; }
            if (gr > 0 && c < NGRID - 1)      { float3 p = ldsP(vs, lr - 1, c + 1); sx += p.x; sy += p.y; sz += p.z; deg++; }
            if (gr < NGRID - 1 && c > 0)      { float3 p = ldsP(vs, lr + 1, c - 1); sx += p.x; sy += p.y; sz += p.z; deg++; }
            const float id = 1.0f / (float)deg;
            const float lx = pc.x - sx * id;
            const float ly = pc.y - sy * id;
            const float lz = pc.z - sz * id;
            lap_sum += lx * lx + ly * ly + lz * lz;
        }

        // Flat loss: up to 3 structural edges anchored at (gr, c)
        // Diagonal edge (r,c+1)-(r+1,c), opposites (r,c),(r+1,c+1)
        if (gr < NGRID - 1 && c < NGRID - 1) {
            flat_sum += edge_val(ldsP(vs, lr, c + 1), ldsP(vs, lr + 1, c),
                                 pc,                  ldsP(vs, lr + 1, c + 1));
        }
        // Horizontal edge (r,c)-(r,c+1), opposites (r+1,c),(r-1,c+1), interior iff 1<=r<=510
        if (gr >= 1 && gr < NGRID - 1 && c < NGRID - 1) {
            flat_sum += edge_val(pc, ldsP(vs, lr, c + 1),
                                 ldsP(vs, lr + 1, c), ldsP(vs, lr - 1, c + 1));
        }
        // Vertical edge (r,c)-(r+1,c), opposites (r,c+1),(r+1,c-1), interior iff 1<=c<=510
        if (gr < NGRID - 1 && c >= 1 && c < NGRID - 1) {
            flat_sum += edge_val(pc, ldsP(vs, lr + 1, c),
                                 ldsP(vs, lr, c + 1), ldsP(vs, lr + 1, c - 1));
        }
    }

    // ---- Block reduction (two values), one atomic pair per block ----
#pragma unroll
    for (int off = 32; off > 0; off >>= 1) {
        lap_sum  += __shfl_down(lap_sum, off, 64);
        flat_sum += __shfl_down(flat_sum, off, 64);
    }
    __shared__ float red[8];
    const int lane = tid & 63;
    const int wid = tid >> 6;
    if (lane == 0) { red[wid] = lap_sum; red[4 + wid] = flat_sum; }
    __syncthreads();
    if (tid == 0) {
        const float ls = red[0] + red[1] + red[2] + red[3];
        const float fs = red[4] + red[5] + red[6] + red[7];
        atomicAdd(&out[LAP_OFF],  ls * (1.0f / NB));
        atomicAdd(&out[FLAT_OFF], fs * (1.0f / NB));
    }
}

// ---------------------------------------------------------------------------
extern "C" void kernel_launch(void* const* d_in, const int* in_sizes, int n_in,
                              void* d_out, int out_size, void* d_ws, size_t ws_size,
                              hipStream_t stream)
{
    const float* disp   = (const float*)d_in[0];
    const float* center = (const float*)d_in[1];
    const float* tex    = (const float*)d_in[2];
    const float* tv     = (const float*)d_in[3];
    float* out = (float*)d_out;

    init_losses<<<1, 64, 0, stream>>>(out);
    mesh_fused_kernel<<<dim3(NGRID / TR, NB), 256, 0, stream>>>(disp, center, tex, tv, out);
}

// Round 4
// 184.150 us; speedup vs baseline: 2.0530x; 1.0875x over previous
//
#include <hip/hip_runtime.h>

#define NGRID 512
#define NV (NGRID * NGRID)          // 262144
#define NB 4
#define NVIEWS 4
#define FEPS 1e-6f
#define TR 2                        // owned rows per block
#define LDS_ROWS (TR + 2)           // + top/bottom halo
#define ROWF (NGRID * 3)            // 1536 floats per row
#define LDSF (LDS_ROWS * ROWF)      // 6144 floats = 24 KB

typedef float fvec4 __attribute__((ext_vector_type(4)));  // native vector, NT-builtin compatible

static constexpr size_t NVF3 = (size_t)NV * 3;                      // 786432
static constexpr size_t VERTS_FLOATS = (size_t)NVIEWS * NB * NVF3;  // 12,582,912
static constexpr size_t LAP_OFF = 2 * VERTS_FLOATS;
static constexpr size_t FLAT_OFF = LAP_OFF + 1;

// ---------------------------------------------------------------------------
__global__ void init_losses(float* __restrict__ out) {
    if (threadIdx.x == 0) {
        out[LAP_OFF] = 0.0f;
        out[FLAT_OFF] = 0.0f;
    }
}

// ---------------------------------------------------------------------------
__device__ __forceinline__ float3 ldsP(const float* __restrict__ vs, int lr, int c) {
    const int o = lr * ROWF + c * 3;
    return make_float3(vs[o], vs[o + 1], vs[o + 2]);
}

__device__ __forceinline__ float edge_val(float3 p0, float3 p1, float3 p2, float3 p3) {
    const float a1x = p1.x - p0.x, a1y = p1.y - p0.y, a1z = p1.z - p0.z;
    const float a1l2 = a1x * a1x + a1y * a1y + a1z * a1z;
    const float a1l1 = sqrtf(a1l2 + FEPS);
    const float inv_a1l2 = 1.0f / (a1l2 + FEPS);

    const float b1x = p2.x - p0.x, b1y = p2.y - p0.y, b1z = p2.z - p0.z;
    const float b1l2 = b1x * b1x + b1y * b1y + b1z * b1z;
    const float b1l1 = sqrtf(b1l2 + FEPS);
    const float ab1 = a1x * b1x + a1y * b1y + a1z * b1z;
    const float cos1 = ab1 / (a1l1 * b1l1 + FEPS);
    const float sin1 = sqrtf(1.0f - cos1 * cos1 + FEPS);
    const float f1 = ab1 * inv_a1l2;
    const float cb1x = b1x - a1x * f1, cb1y = b1y - a1y * f1, cb1z = b1z - a1z * f1;
    const float l1 = b1l1 * sin1;

    const float b2x = p3.x - p0.x, b2y = p3.y - p0.y, b2z = p3.z - p0.z;
    const float b2l2 = b2x * b2x + b2y * b2y + b2z * b2z;
    const float b2l1 = sqrtf(b2l2 + FEPS);
    const float ab2 = a1x * b2x + a1y * b2y + a1z * b2z;
    const float cos2 = ab2 / (a1l1 * b2l1 + FEPS);
    const float sin2 = sqrtf(1.0f - cos2 * cos2 + FEPS);
    const float f2 = ab2 * inv_a1l2;
    const float cb2x = b2x - a1x * f2, cb2y = b2y - a1y * f2, cb2z = b2z - a1z * f2;
    const float l2 = b2l1 * sin2;

    const float cosd = (cb1x * cb2x + cb1y * cb2y + cb1z * cb2z) / (l1 * l2 + FEPS);
    const float t = cosd + 1.0f;
    return t * t;
}

// ---------------------------------------------------------------------------
// Mega-kernel: one block = (2-row tile, batch). Stages v (with 1-row halo)
// in LDS via recompute, writes verts x4 views + tex x4 views (non-temporal),
// computes lap + flat losses for owned rows from LDS.
// Grid: (256, NB) x 256 = 1024 blocks -> 4 blocks/CU resident (24 KB LDS).
__global__ __launch_bounds__(256) void mesh_fused_kernel(
    const float* __restrict__ disp, const float* __restrict__ center,
    const float* __restrict__ tex, const float* __restrict__ tv,
    float* __restrict__ out)
{
    __shared__ float vs[LDSF];
    const int tid = threadIdx.x;
    const int b = blockIdx.y;
    const int R0 = blockIdx.x * TR;

    const float c0 = tanhf(center[b * 3 + 0]);
    const float c1 = tanhf(center[b * 3 + 1]);
    const float c2 = tanhf(center[b * 3 + 2]);
    const float carr[3] = {c0, c1, c2};

    // ---- Stage v for rows [R0-1, R0+TR] into LDS (float4 vectorized) ----
    {
        const fvec4* __restrict__ tv4 = (const fvec4*)tv;
        const fvec4* __restrict__ d4p = (const fvec4*)(disp + (size_t)b * NVF3);
        fvec4* __restrict__ vs4 = (fvec4*)vs;
        const int start4 = (R0 - 1) * (ROWF / 4);          // may be negative (tile 0)
#pragma unroll
        for (int ss = 0; ss < LDSF / 4 / 256; ++ss) {
            const int ff4 = ss * 256 + tid;
            const int g4 = start4 + ff4;
            if (g4 < 0 || g4 >= (int)(NVF3 / 4)) continue;
            const fvec4 t = tv4[g4];
            const fvec4 d = d4p[g4];
            fvec4 vr;
            int comp = ff4 % 3;   // (4*g4)%3 == g4%3 == ff4%3 (start4 % 3 == 0)
#pragma unroll
            for (int l = 0; l < 4; ++l) {
                const float tvl = t[l];
                const float s = fabsf(tvl);
                const float sgn = (tvl > 0.0f) ? 1.0f : -1.0f;
                const float v0 = sgn * (s / (s + (1.0f - s) * expf(-d[l])));
                const float c = carr[comp];
                const float pos = fmaxf(v0, 0.0f);
                const float neg = fmaxf(-v0, 0.0f);
                vr[l] = pos * (1.0f - c) - neg * (c + 1.0f) + c;
                comp = (comp == 2) ? 0 : comp + 1;
            }
            vs4[ff4] = vr;
        }
    }
    __syncthreads();

    // ---- Write verts x4 views + tex x4 views for owned rows (non-temporal) ----
    {
        const fvec4* __restrict__ vs4 = (const fvec4*)vs;
        const fvec4* __restrict__ t4p = (const fvec4*)(tex + (size_t)b * NVF3);
        fvec4* __restrict__ out4 = (fvec4*)out;
        const size_t blk4 = NVF3 / 4;                       // 196608
        const int tile_base4 = R0 * (ROWF / 4);             // float4 offset of row R0
#pragma unroll
        for (int qq = 0; qq < TR * ROWF / 4 / 256; ++qq) {
            const int q = qq * 256 + tid;
            const fvec4 vo = vs4[ROWF / 4 + q];             // skip halo row
            const fvec4 tx = __builtin_nontemporal_load(&t4p[tile_base4 + q]);
            const size_t pos4 = (size_t)tile_base4 + q;
#pragma unroll
            for (int view = 0; view < NVIEWS; ++view) {
                const size_t base = (size_t)(b * NVIEWS + view) * blk4;
                __builtin_nontemporal_store(vo, &out4[base + pos4]);
                __builtin_nontemporal_store(tx, &out4[(VERTS_FLOATS / 4) + base + pos4]);
            }
        }
    }

    // ---- Lap + flat losses for owned rows (reads LDS only) ----
    float lap_sum = 0.0f, flat_sum = 0.0f;
#pragma unroll 1
    for (int it = 0; it < TR * NGRID / 256; ++it) {
        const int idx = it * 256 + tid;
        const int r_off = idx >> 9;            // 0..TR-1
        const int c = idx & (NGRID - 1);
        const int gr = R0 + r_off;             // global row
        const int lr = r_off + 1;              // LDS row

        const float3 pc = ldsP(vs, lr, c);

        // Laplacian
        {
            float sx = 0.f, sy = 0.f, sz = 0.f;
            int deg = 0;
            if (gr > 0)               { float3 p = ldsP(vs, lr - 1, c);     sx += p.x; sy += p.y; sz += p.z; deg++; }
            if (gr < NGRID - 1)       { float3 p = ldsP(vs, lr + 1, c);     sx += p.x; sy += p.y; sz += p.z; deg++; }
            if (c > 0)                { float3 p = ldsP(vs, lr, c - 1);     sx += p.x; sy += p.y; sz += p.z; deg++; }
            if (c < NGRID - 1)        { float3 p = ldsP(vs, lr, c + 1);     sx += p.x; sy += p.y; sz += p.z; deg++; }
            if (gr > 0 && c < NGRID - 1)      { float3 p = ldsP(vs, lr - 1, c + 1); sx += p.x; sy += p.y; sz += p.z; deg++; }
            if (gr < NGRID - 1 && c > 0)      { float3 p = ldsP(vs, lr + 1, c - 1); sx += p.x; sy += p.y; sz += p.z; deg++; }
            const float id = 1.0f / (float)deg;
            const float lx = pc.x - sx * id;
            const float ly = pc.y - sy * id;
            const float lz = pc.z - sz * id;
            lap_sum += lx * lx + ly * ly + lz * lz;
        }

        // Flat loss: up to 3 structural edges anchored at (gr, c)
        // Diagonal edge (r,c+1)-(r+1,c), opposites (r,c),(r+1,c+1)
        if (gr < NGRID - 1 && c < NGRID - 1) {
            flat_sum += edge_val(ldsP(vs, lr, c + 1), ldsP(vs, lr + 1, c),
                                 pc,                  ldsP(vs, lr + 1, c + 1));
        }
        // Horizontal edge (r,c)-(r,c+1), opposites (r+1,c),(r-1,c+1), interior iff 1<=r<=510
        if (gr >= 1 && gr < NGRID - 1 && c < NGRID - 1) {
            flat_sum += edge_val(pc, ldsP(vs, lr, c + 1),
                                 ldsP(vs, lr + 1, c), ldsP(vs, lr - 1, c + 1));
        }
        // Vertical edge (r,c)-(r+1,c), opposites (r,c+1),(r+1,c-1), interior iff 1<=c<=510
        if (gr < NGRID - 1 && c >= 1 && c < NGRID - 1) {
            flat_sum += edge_val(pc, ldsP(vs, lr + 1, c),
                                 ldsP(vs, lr, c + 1), ldsP(vs, lr + 1, c - 1));
        }
    }

    // ---- Block reduction (two values), one atomic pair per block ----
#pragma unroll
    for (int off = 32; off > 0; off >>= 1) {
        lap_sum  += __shfl_down(lap_sum, off, 64);
        flat_sum += __shfl_down(flat_sum, off, 64);
    }
    __shared__ float red[8];
    const int lane = tid & 63;
    const int wid = tid >> 6;
    if (lane == 0) { red[wid] = lap_sum; red[4 + wid] = flat_sum; }
    __syncthreads();
    if (tid == 0) {
        const float ls = red[0] + red[1] + red[2] + red[3];
        const float fs = red[4] + red[5] + red[6] + red[7];
        atomicAdd(&out[LAP_OFF],  ls * (1.0f / NB));
        atomicAdd(&out[FLAT_OFF], fs * (1.0f / NB));
    }
}

// ---------------------------------------------------------------------------
extern "C" void kernel_launch(void* const* d_in, const int* in_sizes, int n_in,
                              void* d_out, int out_size, void* d_ws, size_t ws_size,
                              hipStream_t stream)
{
    const float* disp   = (const float*)d_in[0];
    const float* center = (const float*)d_in[1];
    const float* tex    = (const float*)d_in[2];
    const float* tv     = (const float*)d_in[3];
    float* out = (float*)d_out;

    init_losses<<<1, 64, 0, stream>>>(out);
    mesh_fused_kernel<<<dim3(NGRID / TR, NB), 256, 0, stream>>>(disp, center, tex, tv, out);
}

// Round 5
// 177.244 us; speedup vs baseline: 2.1330x; 1.0390x over previous
//
#include <hip/hip_runtime.h>

#define NGRID 512
#define NV (NGRID * NGRID)          // 262144
#define NB 4
#define NVIEWS 4
#define FEPS 1e-6f
#define TR 2                        // owned rows per block
#define LDS_ROWS (TR + 2)           // + top/bottom halo
#define ROWF (NGRID * 3)            // 1536 floats per row
#define LDSF (LDS_ROWS * ROWF)      // 6144 floats = 24 KB

typedef float fvec4 __attribute__((ext_vector_type(4)));

static constexpr size_t NVF3 = (size_t)NV * 3;                      // 786432
static constexpr size_t VERTS_FLOATS = (size_t)NVIEWS * NB * NVF3;  // 12,582,912
static constexpr size_t LAP_OFF = 2 * VERTS_FLOATS;
static constexpr size_t FLAT_OFF = LAP_OFF + 1;

__device__ __forceinline__ float frcp(float x)  { return __builtin_amdgcn_rcpf(x); }
__device__ __forceinline__ float fsqrt_(float x){ return __builtin_amdgcn_sqrtf(x); }

// ---------------------------------------------------------------------------
__global__ void init_losses(float* __restrict__ out) {
    if (threadIdx.x == 0) {
        out[LAP_OFF] = 0.0f;
        out[FLAT_OFF] = 0.0f;
    }
}

// ---------------------------------------------------------------------------
__device__ __forceinline__ float3 ldsP(const float* __restrict__ vs, int lr, int c) {
    const int o = lr * ROWF + c * 3;
    return make_float3(vs[o], vs[o + 1], vs[o + 2]);
}

__device__ __forceinline__ float edge_val(float3 p0, float3 p1, float3 p2, float3 p3) {
    const float a1x = p1.x - p0.x, a1y = p1.y - p0.y, a1z = p1.z - p0.z;
    const float a1l2 = a1x * a1x + a1y * a1y + a1z * a1z;
    const float a1l1 = fsqrt_(a1l2 + FEPS);
    const float inv_a1l2 = frcp(a1l2 + FEPS);

    const float b1x = p2.x - p0.x, b1y = p2.y - p0.y, b1z = p2.z - p0.z;
    const float b1l2 = b1x * b1x + b1y * b1y + b1z * b1z;
    const float b1l1 = fsqrt_(b1l2 + FEPS);
    const float ab1 = a1x * b1x + a1y * b1y + a1z * b1z;
    const float cos1 = ab1 * frcp(a1l1 * b1l1 + FEPS);
    const float sin1 = fsqrt_(1.0f - cos1 * cos1 + FEPS);
    const float f1 = ab1 * inv_a1l2;
    const float cb1x = b1x - a1x * f1, cb1y = b1y - a1y * f1, cb1z = b1z - a1z * f1;
    const float l1 = b1l1 * sin1;

    const float b2x = p3.x - p0.x, b2y = p3.y - p0.y, b2z = p3.z - p0.z;
    const float b2l2 = b2x * b2x + b2y * b2y + b2z * b2z;
    const float b2l1 = fsqrt_(b2l2 + FEPS);
    const float ab2 = a1x * b2x + a1y * b2y + a1z * b2z;
    const float cos2 = ab2 * frcp(a1l1 * b2l1 + FEPS);
    const float sin2 = fsqrt_(1.0f - cos2 * cos2 + FEPS);
    const float f2 = ab2 * inv_a1l2;
    const float cb2x = b2x - a1x * f2, cb2y = b2y - a1y * f2, cb2z = b2z - a1z * f2;
    const float l2 = b2l1 * sin2;

    const float cosd = (cb1x * cb2x + cb1y * cb2y + cb1z * cb2z) * frcp(l1 * l2 + FEPS);
    const float t = cosd + 1.0f;
    return t * t;
}

// ---------------------------------------------------------------------------
// Mega-kernel: one block = (2-row tile, batch). Stages v (with 1-row halo)
// in LDS via recompute, writes verts x4 views + tex x4 views (non-temporal),
// computes lap + flat losses for owned rows from LDS.
__global__ __launch_bounds__(256) void mesh_fused_kernel(
    const float* __restrict__ disp, const float* __restrict__ center,
    const float* __restrict__ tex, const float* __restrict__ tv,
    float* __restrict__ out)
{
    __shared__ float vs[LDSF];
    const int tid = threadIdx.x;
    const int b = blockIdx.y;
    const int R0 = blockIdx.x * TR;

    const float c0 = tanhf(center[b * 3 + 0]);
    const float c1 = tanhf(center[b * 3 + 1]);
    const float c2 = tanhf(center[b * 3 + 2]);
    const float carr[3] = {c0, c1, c2};

    // ---- Stage v for rows [R0-1, R0+TR] into LDS (float4 vectorized) ----
    {
        const fvec4* __restrict__ tv4 = (const fvec4*)tv;
        const fvec4* __restrict__ d4p = (const fvec4*)(disp + (size_t)b * NVF3);
        fvec4* __restrict__ vs4 = (fvec4*)vs;
        const int start4 = (R0 - 1) * (ROWF / 4);          // may be negative (tile 0)
#pragma unroll
        for (int ss = 0; ss < LDSF / 4 / 256; ++ss) {
            const int ff4 = ss * 256 + tid;
            const int g4 = start4 + ff4;
            if (g4 < 0 || g4 >= (int)(NVF3 / 4)) continue;
            const fvec4 t = tv4[g4];
            const fvec4 d = d4p[g4];
            fvec4 vr;
            int comp = ff4 % 3;   // (4*g4)%3 == g4%3 == ff4%3 (start4 % 3 == 0)
#pragma unroll
            for (int l = 0; l < 4; ++l) {
                const float tvl = t[l];
                const float s = fabsf(tvl);
                const float sgn = (tvl > 0.0f) ? 1.0f : -1.0f;
                // sigma = sigmoid(log(s/(1-s)) + d) = s / (s + (1-s)*exp(-d))
                const float e = __expf(-d[l]);
                const float sigma = s * frcp(fmaf(1.0f - s, e, s));
                // v = relu(v0)(1-c) - relu(-v0)(1+c) + c  ==  sigma*(sgn - c) + c
                const float c = carr[comp];
                vr[l] = fmaf(sigma, sgn - c, c);
                comp = (comp == 2) ? 0 : comp + 1;
            }
            vs4[ff4] = vr;
        }
    }
    __syncthreads();

    // ---- Write verts x4 views + tex x4 views for owned rows (non-temporal) ----
    {
        const fvec4* __restrict__ vs4 = (const fvec4*)vs;
        const fvec4* __restrict__ t4p = (const fvec4*)(tex + (size_t)b * NVF3);
        fvec4* __restrict__ out4 = (fvec4*)out;
        const size_t blk4 = NVF3 / 4;                       // 196608
        const int tile_base4 = R0 * (ROWF / 4);             // float4 offset of row R0
#pragma unroll
        for (int qq = 0; qq < TR * ROWF / 4 / 256; ++qq) {
            const int q = qq * 256 + tid;
            const fvec4 vo = vs4[ROWF / 4 + q];             // skip halo row
            const fvec4 tx = __builtin_nontemporal_load(&t4p[tile_base4 + q]);
            const size_t pos4 = (size_t)tile_base4 + q;
#pragma unroll
            for (int view = 0; view < NVIEWS; ++view) {
                const size_t base = (size_t)(b * NVIEWS + view) * blk4;
                __builtin_nontemporal_store(vo, &out4[base + pos4]);
                __builtin_nontemporal_store(tx, &out4[(VERTS_FLOATS / 4) + base + pos4]);
            }
        }
    }

    // ---- Lap + flat losses for owned rows (reads LDS only) ----
    float lap_sum = 0.0f, flat_sum = 0.0f;
#pragma unroll 1
    for (int it = 0; it < TR * NGRID / 256; ++it) {
        const int idx = it * 256 + tid;
        const int r_off = idx >> 9;            // 0..TR-1
        const int c = idx & (NGRID - 1);
        const int gr = R0 + r_off;             // global row
        const int lr = r_off + 1;              // LDS row

        const float3 pc = ldsP(vs, lr, c);

        // Laplacian
        {
            float sx = 0.f, sy = 0.f, sz = 0.f;
            int deg = 0;
            if (gr > 0)               { float3 p = ldsP(vs, lr - 1, c);     sx += p.x; sy += p.y; sz += p.z; deg++; }
            if (gr < NGRID - 1)       { float3 p = ldsP(vs, lr + 1, c);     sx += p.x; sy += p.y; sz += p.z; deg++; }
            if (c > 0)                { float3 p = ldsP(vs, lr, c - 1);     sx += p.x; sy += p.y; sz += p.z; deg++; }
            if (c < NGRID - 1)        { float3 p = ldsP(vs, lr, c + 1);     sx += p.x; sy += p.y; sz += p.z; deg++; }
            if (gr > 0 && c < NGRID - 1)      { float3 p = ldsP(vs, lr - 1, c + 1); sx += p.x; sy += p.y; sz += p.z; deg++; }
            if (gr < NGRID - 1 && c > 0)      { float3 p = ldsP(vs, lr + 1, c - 1); sx += p.x; sy += p.y; sz += p.z; deg++; }
            const float id = frcp((float)deg);
            const float lx = pc.x - sx * id;
            const float ly = pc.y - sy * id;
            const float lz = pc.z - sz * id;
            lap_sum += lx * lx + ly * ly + lz * lz;
        }

        // Flat loss: up to 3 structural edges anchored at (gr, c)
        if (gr < NGRID - 1 && c < NGRID - 1) {
            flat_sum += edge_val(ldsP(vs, lr, c + 1), ldsP(vs, lr + 1, c),
                                 pc,                  ldsP(vs, lr + 1, c + 1));
        }
        if (gr >= 1 && gr < NGRID - 1 && c < NGRID - 1) {
            flat_sum += edge_val(pc, ldsP(vs, lr, c + 1),
                                 ldsP(vs, lr + 1, c), ldsP(vs, lr - 1, c + 1));
        }
        if (gr < NGRID - 1 && c >= 1 && c < NGRID - 1) {
            flat_sum += edge_val(pc, ldsP(vs, lr + 1, c),
                                 ldsP(vs, lr, c + 1), ldsP(vs, lr + 1, c - 1));
        }
    }

    // ---- Block reduction (two values), one atomic pair per block ----
#pragma unroll
    for (int off = 32; off > 0; off >>= 1) {
        lap_sum  += __shfl_down(lap_sum, off, 64);
        flat_sum += __shfl_down(flat_sum, off, 64);
    }
    __shared__ float red[8];
    const int lane = tid & 63;
    const int wid = tid >> 6;
    if (lane == 0) { red[wid] = lap_sum; red[4 + wid] = flat_sum; }
    __syncthreads();
    if (tid == 0) {
        const float ls = red[0] + red[1] + red[2] + red[3];
        const float fs = red[4] + red[5] + red[6] + red[7];
        atomicAdd(&out[LAP_OFF],  ls * (1.0f / NB));
        atomicAdd(&out[FLAT_OFF], fs * (1.0f / NB));
    }
}

// ---------------------------------------------------------------------------
extern "C" void kernel_launch(void* const* d_in, const int* in_sizes, int n_in,
                              void* d_out, int out_size, void* d_ws, size_t ws_size,
                              hipStream_t stream)
{
    const float* disp   = (const float*)d_in[0];
    const float* center = (const float*)d_in[1];
    const float* tex    = (const float*)d_in[2];
    const float* tv     = (const float*)d_in[3];
    float* out = (float*)d_out;

    init_losses<<<1, 64, 0, stream>>>(out);
    mesh_fused_kernel<<<dim3(NGRID / TR, NB), 256, 0, stream>>>(disp, center, tex, tv, out);
}